// Round 1
// baseline (103.735 us; speedup 1.0000x reference)
//
#include <hip/hip_runtime.h>
#include <math.h>

// SurvLoss: Cox partial-likelihood-style loss with tie grouping.
// Insight: |Y| is an integer in [1,2000]; sorting by signed Y means tie groups
// are distinct signed values (with -1/+1 merged since grouping is on |Y|).
// Negative (censored) groups contribute no events, so:
//   loss2 = sum_t n_events(t) * log(negExpTotal + prefixsum_{u<=t} posExp(u))
//   loss1 = sum(Yhat * [Y>0]);  obs = count(Y>0)
// => histogram over 2000 buckets + tiny double-precision scan. No sort.

#define NBLK 512
#define NT 256
#define NH 2048

__global__ __launch_bounds__(NT) void surv_hist(
    const float* __restrict__ Yhat, const float* __restrict__ Y, int n4,
    float* __restrict__ gExp, unsigned int* __restrict__ gEvt,
    double* __restrict__ negPart, double* __restrict__ loss1Part,
    unsigned long long* __restrict__ obsPart)
{
    __shared__ float sExp[NH];
    __shared__ unsigned int sEvt[NH];
    for (int i = threadIdx.x; i < NH; i += NT) { sExp[i] = 0.f; sEvt[i] = 0u; }
    __syncthreads();

    float negSum = 0.f, loss1 = 0.f;
    unsigned int obs = 0;

    const float4* __restrict__ Y4 = (const float4*)Y;
    const float4* __restrict__ H4 = (const float4*)Yhat;
    const int stride = NBLK * NT;
    for (int i = blockIdx.x * NT + threadIdx.x; i < n4; i += stride) {
        float4 y = Y4[i];
        float4 h = H4[i];
        float ys[4] = {y.x, y.y, y.z, y.w};
        float hs[4] = {h.x, h.y, h.z, h.w};
        #pragma unroll
        for (int c = 0; c < 4; ++c) {
            float e = __expf(hs[c]);
            if (ys[c] > 0.f) {
                int t = (int)ys[c];           // t in [1,2000] < NH
                atomicAdd(&sExp[t], e);
                atomicAdd(&sEvt[t], 1u);
                loss1 += hs[c];
                obs += 1u;
            } else {
                negSum += e;
            }
        }
    }

    // wave (64-lane) reduce of scalars
    #pragma unroll
    for (int off = 32; off > 0; off >>= 1) {
        negSum += __shfl_down(negSum, off);
        loss1  += __shfl_down(loss1, off);
        obs    += __shfl_down(obs, off);
    }
    __shared__ float wNeg[NT / 64], wL1[NT / 64];
    __shared__ unsigned int wObs[NT / 64];
    const int lane = threadIdx.x & 63, wid = threadIdx.x >> 6;
    if (lane == 0) { wNeg[wid] = negSum; wL1[wid] = loss1; wObs[wid] = obs; }
    __syncthreads();  // also guarantees all LDS hist atomics are complete
    if (threadIdx.x == 0) {
        double nn = 0.0, ll = 0.0; unsigned long long oo = 0ull;
        #pragma unroll
        for (int w = 0; w < NT / 64; ++w) {
            nn += (double)wNeg[w]; ll += (double)wL1[w]; oo += wObs[w];
        }
        negPart[blockIdx.x] = nn;
        loss1Part[blockIdx.x] = ll;
        obsPart[blockIdx.x] = oo;
    }

    // flush per-block LDS histogram to global (zeroed by hipMemsetAsync)
    for (int i = threadIdx.x; i < NH; i += NT) {
        float v = sExp[i];
        unsigned int c = sEvt[i];
        if (v != 0.f) atomicAdd(&gExp[i], v);
        if (c != 0u)  atomicAdd(&gEvt[i], c);
    }
}

__global__ __launch_bounds__(NT) void surv_final(
    const float* __restrict__ gExp, const unsigned int* __restrict__ gEvt,
    const double* __restrict__ negPart, const double* __restrict__ loss1Part,
    const unsigned long long* __restrict__ obsPart, float* __restrict__ out)
{
    const int tid = threadIdx.x;
    __shared__ double sA[NT];

    // reduce per-block scalar partials (NBLK == 2*NT)
    double nP = negPart[tid] + negPart[tid + NT];
    double lP = loss1Part[tid] + loss1Part[tid + NT];
    double oP = (double)(obsPart[tid] + obsPart[tid + NT]);

    sA[tid] = nP; __syncthreads();
    for (int off = NT / 2; off > 0; off >>= 1) { if (tid < off) sA[tid] += sA[tid + off]; __syncthreads(); }
    const double negTotal = sA[0]; __syncthreads();

    sA[tid] = lP; __syncthreads();
    for (int off = NT / 2; off > 0; off >>= 1) { if (tid < off) sA[tid] += sA[tid + off]; __syncthreads(); }
    const double loss1 = sA[0]; __syncthreads();

    sA[tid] = oP; __syncthreads();
    for (int off = NT / 2; off > 0; off >>= 1) { if (tid < off) sA[tid] += sA[tid + off]; __syncthreads(); }
    const double obs = sA[0]; __syncthreads();

    // each thread owns 8 consecutive buckets (ascending t across threads)
    const int C = NH / NT;  // 8
    double pe[C]; unsigned int ev[C];
    double csum = 0.0;
    const int base = tid * C;
    #pragma unroll
    for (int j = 0; j < C; ++j) {
        pe[j] = (double)gExp[base + j];
        ev[j] = gEvt[base + j];
        csum += pe[j];
    }

    // Hillis-Steele inclusive scan of per-thread chunk sums (double)
    sA[tid] = csum; __syncthreads();
    for (int off = 1; off < NT; off <<= 1) {
        double add = (tid >= off) ? sA[tid - off] : 0.0;
        __syncthreads();
        sA[tid] += add;
        __syncthreads();
    }
    const double excl = sA[tid] - csum;
    __syncthreads();

    double prefix = negTotal + excl;
    double loss2 = 0.0;
    #pragma unroll
    for (int j = 0; j < C; ++j) {
        prefix += pe[j];
        if (ev[j]) loss2 += (double)ev[j] * log(prefix);
    }

    sA[tid] = loss2; __syncthreads();
    for (int off = NT / 2; off > 0; off >>= 1) { if (tid < off) sA[tid] += sA[tid + off]; __syncthreads(); }
    if (tid == 0) out[0] = (float)((sA[0] - loss1) / obs);
}

extern "C" void kernel_launch(void* const* d_in, const int* in_sizes, int n_in,
                              void* d_out, int out_size, void* d_ws, size_t ws_size,
                              hipStream_t stream)
{
    const float* Yhat = (const float*)d_in[0];
    const float* Y    = (const float*)d_in[1];
    const int n = in_sizes[0];

    char* ws = (char*)d_ws;
    float* gExp              = (float*)(ws + 0);
    unsigned int* gEvt       = (unsigned int*)(ws + NH * 4);
    double* negPart          = (double*)(ws + NH * 8);
    double* loss1Part        = (double*)(ws + NH * 8 + NBLK * 8);
    unsigned long long* obsPart = (unsigned long long*)(ws + NH * 8 + 2 * NBLK * 8);

    // zero the atomic-accumulated histogram region (16 KB); ws is re-poisoned
    // to 0xAA before every timed launch, so this must run every call.
    hipMemsetAsync(ws, 0, NH * 8, stream);

    surv_hist<<<NBLK, NT, 0, stream>>>(Yhat, Y, n / 4, gExp, gEvt,
                                       negPart, loss1Part, obsPart);
    surv_final<<<1, NT, 0, stream>>>(gExp, gEvt, negPart, loss1Part, obsPart,
                                     (float*)d_out);
}

// Round 2
// 97.428 us; speedup vs baseline: 1.0647x; 1.0647x over previous
//
#include <hip/hip_runtime.h>
#include <math.h>

// SurvLoss: Cox partial-likelihood loss with tie grouping.
// |Y| is an integer in [1,2000]; sorted order is -2000..-1,1..2000, so
//   loss2 = sum_t n_events(t) * log(negExpTotal + prefix_{u<=t} posExp(u))
//   loss1 = sum(Yhat * [Y>0]);  obs = count(Y>0)
// => 2000-bucket histogram + tiny double-precision scan. No sort.
//
// R2: replaced the 2M contended device-scope atomics (512 blocks flushing
// into one 16 KB histogram across 8 XCDs) with non-atomic per-block
// histogram dumps (8 MB streaming) + a tiled tree-reduce kernel whose
// final merge is only 131K atomics with 32 contenders/address.

#define NBLK 512
#define NT 256
#define NH 2048

__global__ __launch_bounds__(NT) void surv_hist(
    const float* __restrict__ Yhat, const float* __restrict__ Y, int n4,
    float* __restrict__ Exp, unsigned int* __restrict__ Evt,
    double* __restrict__ negPart, double* __restrict__ loss1Part,
    unsigned long long* __restrict__ obsPart)
{
    __shared__ float sExp[NH];
    __shared__ unsigned int sEvt[NH];
    for (int i = threadIdx.x; i < NH; i += NT) { sExp[i] = 0.f; sEvt[i] = 0u; }
    __syncthreads();

    float negSum = 0.f, loss1 = 0.f;
    unsigned int obs = 0;

    const float4* __restrict__ Y4 = (const float4*)Y;
    const float4* __restrict__ H4 = (const float4*)Yhat;
    const int stride = NBLK * NT;
    for (int i = blockIdx.x * NT + threadIdx.x; i < n4; i += stride) {
        float4 y = Y4[i];
        float4 h = H4[i];
        float ys[4] = {y.x, y.y, y.z, y.w};
        float hs[4] = {h.x, h.y, h.z, h.w};
        #pragma unroll
        for (int c = 0; c < 4; ++c) {
            float e = __expf(hs[c]);
            if (ys[c] > 0.f) {
                int t = (int)ys[c];           // t in [1,2000] < NH
                atomicAdd(&sExp[t], e);       // LDS atomic, random bucket
                atomicAdd(&sEvt[t], 1u);
                loss1 += hs[c];
                obs += 1u;
            } else {
                negSum += e;
            }
        }
    }

    // wave (64-lane) reduce of scalars
    #pragma unroll
    for (int off = 32; off > 0; off >>= 1) {
        negSum += __shfl_down(negSum, off);
        loss1  += __shfl_down(loss1, off);
        obs    += __shfl_down(obs, off);
    }
    __shared__ float wNeg[NT / 64], wL1[NT / 64];
    __shared__ unsigned int wObs[NT / 64];
    const int lane = threadIdx.x & 63, wid = threadIdx.x >> 6;
    if (lane == 0) { wNeg[wid] = negSum; wL1[wid] = loss1; wObs[wid] = obs; }
    __syncthreads();  // also guarantees all LDS hist atomics are complete
    if (threadIdx.x == 0) {
        double nn = 0.0, ll = 0.0; unsigned long long oo = 0ull;
        #pragma unroll
        for (int w = 0; w < NT / 64; ++w) {
            nn += (double)wNeg[w]; ll += (double)wL1[w]; oo += wObs[w];
        }
        negPart[blockIdx.x] = nn;
        loss1Part[blockIdx.x] = ll;
        obsPart[blockIdx.x] = oo;
    }

    // non-atomic coalesced dump of this block's histogram row
    float* __restrict__ myExp = Exp + (size_t)blockIdx.x * NH;
    unsigned int* __restrict__ myEvt = Evt + (size_t)blockIdx.x * NH;
    for (int i = threadIdx.x; i < NH; i += NT) {
        myExp[i] = sExp[i];
        myEvt[i] = sEvt[i];
    }
}

// Sum the 512 x 2048 per-block histograms down to one 2048-bucket histogram.
// Grid = 256 blocks: 8 column-chunks (256 cols each) x 32 row-chunks (16 rows).
// One atomicAdd per thread per array -> only 32 contenders per address.
__global__ __launch_bounds__(NT) void surv_reduce(
    const float* __restrict__ Exp, const unsigned int* __restrict__ Evt,
    float* __restrict__ gExp, unsigned int* __restrict__ gEvt)
{
    const int col = (blockIdx.x & 7) * NT + threadIdx.x;
    const int r0 = (blockIdx.x >> 3) * 16;
    float a = 0.f;
    unsigned int c = 0u;
    #pragma unroll
    for (int r = 0; r < 16; ++r) {
        a += Exp[(size_t)(r0 + r) * NH + col];
        c += Evt[(size_t)(r0 + r) * NH + col];
    }
    atomicAdd(&gExp[col], a);
    atomicAdd(&gEvt[col], c);
}

__global__ __launch_bounds__(NT) void surv_final(
    const float* __restrict__ gExp, const unsigned int* __restrict__ gEvt,
    const double* __restrict__ negPart, const double* __restrict__ loss1Part,
    const unsigned long long* __restrict__ obsPart, float* __restrict__ out)
{
    const int tid = threadIdx.x;
    __shared__ double sA[NT];

    // reduce per-block scalar partials (NBLK == 2*NT)
    double nP = negPart[tid] + negPart[tid + NT];
    double lP = loss1Part[tid] + loss1Part[tid + NT];
    double oP = (double)(obsPart[tid] + obsPart[tid + NT]);

    sA[tid] = nP; __syncthreads();
    for (int off = NT / 2; off > 0; off >>= 1) { if (tid < off) sA[tid] += sA[tid + off]; __syncthreads(); }
    const double negTotal = sA[0]; __syncthreads();

    sA[tid] = lP; __syncthreads();
    for (int off = NT / 2; off > 0; off >>= 1) { if (tid < off) sA[tid] += sA[tid + off]; __syncthreads(); }
    const double loss1 = sA[0]; __syncthreads();

    sA[tid] = oP; __syncthreads();
    for (int off = NT / 2; off > 0; off >>= 1) { if (tid < off) sA[tid] += sA[tid + off]; __syncthreads(); }
    const double obs = sA[0]; __syncthreads();

    // each thread owns 8 consecutive buckets (ascending t across threads)
    const int C = NH / NT;  // 8
    double pe[C]; unsigned int ev[C];
    double csum = 0.0;
    const int base = tid * C;
    #pragma unroll
    for (int j = 0; j < C; ++j) {
        pe[j] = (double)gExp[base + j];
        ev[j] = gEvt[base + j];
        csum += pe[j];
    }

    // Hillis-Steele inclusive scan of per-thread chunk sums (double)
    sA[tid] = csum; __syncthreads();
    for (int off = 1; off < NT; off <<= 1) {
        double add = (tid >= off) ? sA[tid - off] : 0.0;
        __syncthreads();
        sA[tid] += add;
        __syncthreads();
    }
    const double excl = sA[tid] - csum;
    __syncthreads();

    double prefix = negTotal + excl;
    double loss2 = 0.0;
    #pragma unroll
    for (int j = 0; j < C; ++j) {
        prefix += pe[j];
        if (ev[j]) loss2 += (double)ev[j] * log(prefix);
    }

    sA[tid] = loss2; __syncthreads();
    for (int off = NT / 2; off > 0; off >>= 1) { if (tid < off) sA[tid] += sA[tid + off]; __syncthreads(); }
    if (tid == 0) out[0] = (float)((sA[0] - loss1) / obs);
}

extern "C" void kernel_launch(void* const* d_in, const int* in_sizes, int n_in,
                              void* d_out, int out_size, void* d_ws, size_t ws_size,
                              hipStream_t stream)
{
    const float* Yhat = (const float*)d_in[0];
    const float* Y    = (const float*)d_in[1];
    const int n = in_sizes[0];

    char* ws = (char*)d_ws;
    // layout: per-block hist dumps, then final histogram, then scalar partials
    float* Exp               = (float*)(ws);                         // 4 MB
    unsigned int* Evt        = (unsigned int*)(ws + (size_t)NBLK * NH * 4);  // 4 MB
    char* tail               = ws + 2ull * NBLK * NH * 4;
    float* gExp              = (float*)(tail);                       // 8 KB
    unsigned int* gEvt       = (unsigned int*)(tail + NH * 4);       // 8 KB
    double* negPart          = (double*)(tail + NH * 8);             // 4 KB
    double* loss1Part        = (double*)(tail + NH * 8 + NBLK * 8);  // 4 KB
    unsigned long long* obsPart = (unsigned long long*)(tail + NH * 8 + 2 * NBLK * 8);

    // zero only the atomically-merged final histogram (16 KB)
    hipMemsetAsync(tail, 0, NH * 8, stream);

    surv_hist<<<NBLK, NT, 0, stream>>>(Yhat, Y, n / 4, Exp, Evt,
                                       negPart, loss1Part, obsPart);
    surv_reduce<<<256, NT, 0, stream>>>(Exp, Evt, gExp, gEvt);
    surv_final<<<1, NT, 0, stream>>>(gExp, gEvt, negPart, loss1Part, obsPart,
                                     (float*)d_out);
}